// Round 11
// baseline (317.886 us; speedup 1.0000x reference)
//
#include <hip/hip_runtime.h>

#define N_ROWS 8192
#define DIM 256
#define EPSF 1e-8f

typedef _Float16 f16x8 __attribute__((ext_vector_type(8)));
typedef float f32x4 __attribute__((ext_vector_type(4)));

// ---------------------------------------------------------------------------
// D1: inv_norm (fp32) + fp64 column-sums of x_hat via LDS reduce + one
// f64 atomicAdd per thread (proven r1-r10).  512 blocks x 16 rows.
// ---------------------------------------------------------------------------
__global__ __launch_bounds__(256) void k1_norm(const float* __restrict__ T,
                                               float* __restrict__ inv_norm,
                                               double* __restrict__ s) {
    __shared__ double sacc[4][DIM];
    const int tid = threadIdx.x, bid = blockIdx.x;
    const int lane = tid & 63, wave = tid >> 6;
    double a0 = 0, a1 = 0, a2 = 0, a3 = 0;
#pragma unroll
    for (int r = 0; r < 4; ++r) {
        int row = bid * 16 + wave * 4 + r;
        float4 v = ((const float4*)(T + (size_t)row * DIM))[lane];
        float ss = v.x * v.x + v.y * v.y + v.z * v.z + v.w * v.w;
#pragma unroll
        for (int o = 32; o; o >>= 1) ss += __shfl_down(ss, o);
        ss = __shfl(ss, 0);
        float inv = 1.0f / fmaxf(sqrtf(ss), EPSF);
        if (lane == 0) inv_norm[row] = inv;
        a0 += (double)(v.x * inv);
        a1 += (double)(v.y * inv);
        a2 += (double)(v.z * inv);
        a3 += (double)(v.w * inv);
    }
    sacc[wave][lane * 4 + 0] = a0;
    sacc[wave][lane * 4 + 1] = a1;
    sacc[wave][lane * 4 + 2] = a2;
    sacc[wave][lane * 4 + 3] = a3;
    __syncthreads();
    double t = sacc[0][tid] + sacc[1][tid] + sacc[2][tid] + sacc[3][tid];
    atomicAdd(&s[tid], t);
}

// ---------------------------------------------------------------------------
// D2: ALL remaining phases in one dispatch, block-role split + device-scope
// flag chain (G16: threadfence + device atomics; consumers spin w/ s_sleep).
//   blocks    0..511  gemm:    M-partials (fp16 MFMA, dbuf LDS)   -> ctr[0]
//   blocks  512..1023 rs:      inv_rs, 4 fp64 row-dots per wave   -> ctr[1]
//   blocks 1024..1087 reduceM: partials -> Mt (spins ctr[0]==512) -> ctr[2]
//   blocks 1088..1599 k3:      out (spins ctr[1]==512, ctr[2]==64)
// DEADLOCK-FREE BY CO-RESIDENCY: LDS 20480 B -> 8 blk/CU; launch_bounds
// (256,7) forces VGPR<=73 -> >=7 blk/CU -> capacity 1792 >= 1600 total, so
// every block is resident and producers always run.  Deps point low->high id.
// ---------------------------------------------------------------------------
__global__ __launch_bounds__(256, 7) void k2_all(
    const float* __restrict__ T, const float* __restrict__ inv_norm,
    const double* __restrict__ s, float* __restrict__ inv_rs,
    float* __restrict__ partials, _Float16* __restrict__ Mt,
    float* __restrict__ out, int* __restrict__ counters)
{
    __shared__ _Float16 As[2][64][40];   // 10240 B (shared by gemm & k3 roles)
    __shared__ _Float16 Bs[2][64][40];   // 10240 B
    const int tid = threadIdx.x, bid = blockIdx.x;
    const int lane = tid & 63, wave = tid >> 6;

    if (bid < 512) {
        // ---- gemm role (r10-verified): g = bid, (kx,dy,z) = (4,4,32)
        const int g = bid;
        const int k0 = (g & 3) * 64;
        const int d0 = ((g >> 2) & 3) * 64;
        const int i0 = (g >> 4) * 256;
        const int wy = wave >> 1, wx = wave & 1;
        const int lm = lane & 15, lg = lane >> 4;
        const int i = tid & 31, c8 = (tid >> 5) * 8;
        f32x4 acc[2][2] = {};
        float4 rA[2], rB[2];
        float rI;

        auto stage = [&](int ic) {
            int gi = i0 + ic + i;
            rI = inv_norm[gi];
            const float* rowp = T + (size_t)gi * DIM;
            rA[0] = *(const float4*)(rowp + k0 + c8);
            rA[1] = *(const float4*)(rowp + k0 + c8 + 4);
            rB[0] = *(const float4*)(rowp + d0 + c8);
            rB[1] = *(const float4*)(rowp + d0 + c8 + 4);
        };
        auto commit = [&](int buf) {
#pragma unroll
            for (int j = 0; j < 2; ++j) {
                float4 a = rA[j], b = rB[j];
                int c = c8 + j * 4;
                As[buf][c + 0][i] = (_Float16)(a.x * rI);
                As[buf][c + 1][i] = (_Float16)(a.y * rI);
                As[buf][c + 2][i] = (_Float16)(a.z * rI);
                As[buf][c + 3][i] = (_Float16)(a.w * rI);
                Bs[buf][c + 0][i] = (_Float16)b.x;
                Bs[buf][c + 1][i] = (_Float16)b.y;
                Bs[buf][c + 2][i] = (_Float16)b.z;
                Bs[buf][c + 3][i] = (_Float16)b.w;
            }
        };
        auto compute = [&](int buf) {
            f16x8 af[2], bf[2];
#pragma unroll
            for (int mt = 0; mt < 2; ++mt)
                af[mt] = *(const f16x8*)&As[buf][wy * 32 + mt * 16 + lm][lg * 8];
#pragma unroll
            for (int nt = 0; nt < 2; ++nt)
                bf[nt] = *(const f16x8*)&Bs[buf][wx * 32 + nt * 16 + lm][lg * 8];
#pragma unroll
            for (int mt = 0; mt < 2; ++mt)
#pragma unroll
                for (int nt = 0; nt < 2; ++nt)
                    acc[mt][nt] = __builtin_amdgcn_mfma_f32_16x16x32_f16(
                        af[mt], bf[nt], acc[mt][nt], 0, 0, 0);
        };

        stage(0);
        commit(0);
        __syncthreads();
        for (int c = 1; c < 8; ++c) {
            stage(c * 32);
            compute((c - 1) & 1);
            commit(c & 1);
            __syncthreads();
        }
        compute(1);

        float* pz = partials + (size_t)(g >> 4) * 65536;
#pragma unroll
        for (int mt = 0; mt < 2; ++mt) {
            int km = k0 + wy * 32 + mt * 16 + lg * 4;
#pragma unroll
            for (int nt = 0; nt < 2; ++nt) {
                int dn = d0 + wx * 32 + nt * 16 + lm;
#pragma unroll
                for (int r = 0; r < 4; ++r)
                    pz[(size_t)(km + r) * 256 + dn] = acc[mt][nt][r];
            }
        }
        __threadfence();
        __syncthreads();
        if (tid == 0) atomicAdd(&counters[0], 1);
        return;
    }

    if (bid < 1024) {
        // ---- rs role: 16 rows/block, 4 fp64 row-dots per wave
        // (precision-critical: rs ~6e-4 possible; fp64 keeps err ~1e-9)
        const int base = (bid - 512) * 16 + wave * 4;
        const double s0 = s[lane * 4 + 0];
        const double s1 = s[lane * 4 + 1];
        const double s2 = s[lane * 4 + 2];
        const double s3 = s[lane * 4 + 3];
#pragma unroll
        for (int r = 0; r < 4; ++r) {
            int row = base + r;
            float4 v = ((const float4*)(T + (size_t)row * DIM))[lane];
            double d = (double)v.x * s0 + (double)v.y * s1 +
                       (double)v.z * s2 + (double)v.w * s3;
#pragma unroll
            for (int o = 32; o; o >>= 1) d += __shfl_down(d, o);
            if (lane == 0)
                inv_rs[row] = (float)(1.0 / (d * (double)inv_norm[row]));
        }
        __threadfence();
        __syncthreads();
        if (tid == 0) atomicAdd(&counters[1], 1);
        return;
    }

    if (bid < 1088) {
        // ---- reduceM role: 64 blocks x 1024 outputs; waits for gemm
        if (tid == 0)
            while (atomicAdd(&counters[0], 0) < 512) __builtin_amdgcn_s_sleep(8);
        __syncthreads();
        __threadfence();
        const int b = bid - 1024;
#pragma unroll
        for (int q = 0; q < 4; ++q) {
            int g = b * 1024 + q * 256 + tid;
            int k = g >> 8, d = g & 255;
            const float* p = partials + (size_t)k * 256 + d;
            float a0 = 0.f, a1 = 0.f, a2 = 0.f, a3 = 0.f;
#pragma unroll
            for (int z = 0; z < 32; z += 4) {
                a0 += p[(size_t)(z + 0) * 65536];
                a1 += p[(size_t)(z + 1) * 65536];
                a2 += p[(size_t)(z + 2) * 65536];
                a3 += p[(size_t)(z + 3) * 65536];
            }
            Mt[(size_t)d * 256 + k] = (_Float16)((a0 + a1) + (a2 + a3));
        }
        __threadfence();
        __syncthreads();
        if (tid == 0) atomicAdd(&counters[2], 1);
        return;
    }

    // ---- k3 role: 512 blocks, 64x64 tile (r4-verified layout), dbuf LDS.
    // Waits for rs (inv_rs) and reduceM (Mt).
    {
        if (tid == 0) {
            while (atomicAdd(&counters[2], 0) < 64) __builtin_amdgcn_s_sleep(8);
            while (atomicAdd(&counters[1], 0) < 512) __builtin_amdgcn_s_sleep(8);
        }
        __syncthreads();
        __threadfence();

        const int t = bid - 1088;
        const int i0 = (t >> 2) * 64;
        const int d0 = (t & 3) * 64;
        const int wy = wave >> 1, wx = wave & 1;
        const int lm = lane & 15, lg = lane >> 4;
        f32x4 acc[2][2] = {};
        float4 rA[2];
        float rI[2];
        f16x8 rB;
        const int db = tid >> 2, k8 = (tid & 3) * 8;

        auto stage = [&](int kc) {
#pragma unroll
            for (int j = 0; j < 2; ++j) {
                int idx = tid + 256 * j;
                int ia = idx >> 3;
                int c4 = (idx & 7) * 4;
                int gi = i0 + ia;
                rI[j] = inv_norm[gi];
                rA[j] = *(const float4*)(T + (size_t)gi * DIM + kc + c4);
            }
            rB = *(const f16x8*)(Mt + (size_t)(d0 + db) * 256 + kc + k8);
        };
        auto commit = [&](int buf) {
#pragma unroll
            for (int j = 0; j < 2; ++j) {
                int idx = tid + 256 * j;
                int ia = idx >> 3;
                int c4 = (idx & 7) * 4;
                float inv = rI[j];
                As[buf][ia][c4 + 0] = (_Float16)(rA[j].x * inv);
                As[buf][ia][c4 + 1] = (_Float16)(rA[j].y * inv);
                As[buf][ia][c4 + 2] = (_Float16)(rA[j].z * inv);
                As[buf][ia][c4 + 3] = (_Float16)(rA[j].w * inv);
            }
            *(f16x8*)&Bs[buf][db][k8] = rB;
        };
        auto compute = [&](int buf) {
            f16x8 af[2], bf[2];
#pragma unroll
            for (int ti = 0; ti < 2; ++ti)
                af[ti] = *(const f16x8*)&As[buf][wy * 32 + ti * 16 + lm][lg * 8];
#pragma unroll
            for (int tj = 0; tj < 2; ++tj)
                bf[tj] = *(const f16x8*)&Bs[buf][wx * 32 + tj * 16 + lm][lg * 8];
#pragma unroll
            for (int ti = 0; ti < 2; ++ti)
#pragma unroll
                for (int tj = 0; tj < 2; ++tj)
                    acc[ti][tj] = __builtin_amdgcn_mfma_f32_16x16x32_f16(
                        af[ti], bf[tj], acc[ti][tj], 0, 0, 0);
        };

        stage(0);
        commit(0);
        __syncthreads();
        for (int c = 1; c < 8; ++c) {
            stage(c * 32);
            compute((c - 1) & 1);
            commit(c & 1);
            __syncthreads();
        }
        compute(1);

#pragma unroll
        for (int ti = 0; ti < 2; ++ti) {
#pragma unroll
            for (int r = 0; r < 4; ++r) {
                int gi = i0 + wy * 32 + ti * 16 + lg * 4 + r;
                float ir = inv_rs[gi];
#pragma unroll
                for (int tj = 0; tj < 2; ++tj)
                    out[(size_t)gi * DIM + d0 + wx * 32 + tj * 16 + lm] =
                        acc[ti][tj][r] * ir;
            }
        }
    }
}

// ---------------------------------------------------------------------------
extern "C" void kernel_launch(void* const* d_in, const int* in_sizes, int n_in,
                              void* d_out, int out_size, void* d_ws, size_t ws_size,
                              hipStream_t stream) {
    const float* T = (const float*)d_in[0];
    float* out = (float*)d_out;

    // workspace layout (16B-aligned, ~8.6 MB of 256 MiB):
    //   [0,       32768)   inv_norm  float[8192]
    //   [32768,   34816)   s         double[256]
    //   [34816,   34880)   counters  int[16]      (zeroed with s, one memset)
    //   [34880,   67648)   inv_rs    float[8192]
    //   [67648,   198720)  Mt        _Float16[256][256]  (M transposed)
    //   [198720,  +8 MiB)  partials  float[32][256][256]
    char* ws = (char*)d_ws;
    float* inv_norm = (float*)(ws);
    double* s = (double*)(ws + 32768);
    int* counters = (int*)(ws + 34816);
    float* inv_rs = (float*)(ws + 34880);
    _Float16* Mt = (_Float16*)(ws + 67648);
    float* partials = (float*)(ws + 198720);

    hipMemsetAsync(ws + 32768, 0, 2112, stream);   // s + counters
    k1_norm<<<512, 256, 0, stream>>>(T, inv_norm, s);
    k2_all<<<1600, 256, 0, stream>>>(T, inv_norm, s, inv_rs, partials, Mt,
                                     out, counters);
}